// Round 1
// baseline (680.426 us; speedup 1.0000x reference)
//
#include <hip/hip_runtime.h>
#include <math.h>

// Swin-style window attention, WS=8, HEADS=3, C=48, hd=16, fp32.
// X: [B,48,512,512] -> out: [B,48,512,512]. 8192 independent 8x8 windows.

// ---------------- kernel 1: relative-position-bias MLP (once per launch) ----
// bias[h][n][m] = m2b[h] + sum_k m2w[h][k] * relu(m1b[k] + m1w[k][0]*r0 + m1w[k][1]*r1)
__global__ __launch_bounds__(256) void bias_mlp_kernel(
    const float* __restrict__ m1w, const float* __restrict__ m1b,
    const float* __restrict__ m2w, const float* __restrict__ m2b,
    float* __restrict__ biasws)
{
    int t = blockIdx.x * 256 + threadIdx.x;   // 0..4095 -> (n,m)
    int n = t >> 6, m = t & 63;
    float di = (float)((n >> 3) - (m >> 3));
    float dj = (float)((n & 7) - (m & 7));
    float r0 = copysignf(log1pf(fabsf(di)), di);
    float r1 = copysignf(log1pf(fabsf(dj)), dj);
    float a0 = 0.f, a1 = 0.f, a2 = 0.f;
    for (int k = 0; k < 256; ++k) {
        float hpre = m1b[k] + m1w[2*k]*r0 + m1w[2*k+1]*r1;
        float hv = fmaxf(hpre, 0.f);
        a0 += m2w[k]     * hv;
        a1 += m2w[256+k] * hv;
        a2 += m2w[512+k] * hv;
    }
    biasws[t]        = a0 + m2b[0];
    biasws[4096 + t] = a1 + m2b[1];
    biasws[8192 + t] = a2 + m2b[2];
}

// ---------------- kernel 2: fused QKV-proj + window attention + out-proj ----
__global__ __launch_bounds__(256) void win_attn_kernel(
    const float* __restrict__ X,
    const float* __restrict__ v_w,  const float* __restrict__ v_b,
    const float* __restrict__ qk_w, const float* __restrict__ qk_b,
    const float* __restrict__ proj_w, const float* __restrict__ proj_b,
    const float* __restrict__ biasws,
    float* __restrict__ out)
{
    // LDS: 80 KB total -> 2 blocks/CU
    __shared__ float sXs[48*64];     // X window [c][p]; reused as attn-out Os[c][p]
    __shared__ float sWu[144*48];    // union: Wqkv[144][48]; later S[64][stride68] + Pw[48][48]@4352
    __shared__ float sQKV[144*64];   // [channel][token]; q rows 0..47, k 48..95, v 96..143
    __shared__ float sQKVb[144];
    __shared__ float sPb[48];
    __shared__ float sLsum[64];

    const int tid   = threadIdx.x;
    const int blk   = blockIdx.x;
    const int batch = blk >> 12;           // 64*64 windows per image
    const int wh    = (blk >> 6) & 63;
    const int ww    = blk & 63;
    const int h0    = wh << 3, w0 = ww << 3;

    // ---- phase 1: stage X window + weights/biases ----
    const float* Xb = X + ((size_t)batch * 48 << 18);
    for (int idx = tid; idx < 3072; idx += 256) {
        int c = idx >> 6, p = idx & 63;
        sXs[idx] = Xb[((size_t)c << 18) + (size_t)(h0 + (p >> 3)) * 512 + (w0 + (p & 7))];
    }
    for (int idx = tid; idx < 6912; idx += 256)
        sWu[idx] = (idx < 4608) ? qk_w[idx] : v_w[idx - 4608];
    if (tid < 144) sQKVb[tid] = (tid < 96) ? qk_b[tid] : v_b[tid - 96];
    if (tid < 48)  sPb[tid]   = proj_b[tid];
    __syncthreads();

    // ---- phase 2: QKV[o][p] = Wqkv[o][:] . Xs[:][p] + b  (9x4 micro-tile/thread) ----
    {
        const int og = tid >> 4;       // 0..15 -> 9 output channels each
        const int pg = tid & 15;       // 0..15 -> 4 tokens each
        const int ob = og * 9, pb4 = pg * 4;
        float acc[9][4];
        #pragma unroll
        for (int j = 0; j < 9; ++j) {
            float bv = sQKVb[ob + j];
            acc[j][0] = acc[j][1] = acc[j][2] = acc[j][3] = bv;
        }
        for (int c = 0; c < 48; ++c) {
            float4 x4 = *(const float4*)&sXs[c*64 + pb4];
            #pragma unroll
            for (int j = 0; j < 9; ++j) {
                float w = sWu[(ob + j)*48 + c];
                acc[j][0] += w * x4.x; acc[j][1] += w * x4.y;
                acc[j][2] += w * x4.z; acc[j][3] += w * x4.w;
            }
        }
        #pragma unroll
        for (int j = 0; j < 9; ++j)
            *(float4*)&sQKV[(ob + j)*64 + pb4] =
                make_float4(acc[j][0], acc[j][1], acc[j][2], acc[j][3]);
    }
    __syncthreads();   // Wqkv region now free for S/Pw

    // ---- phase 2b: load proj weights into union tail (read only in phase 4) ----
    for (int idx = tid; idx < 2304; idx += 256)
        sWu[4352 + idx] = proj_w[idx];

    float* S = sWu;                        // [64 rows][stride 68]
    const float* Pw = sWu + 4352;          // [48][48]
    const float scale = 0.25f;             // hd=16 -> 1/sqrt(16)

    for (int h = 0; h < 3; ++h) {
        // ---- scores: S[n][m] = scale * q.k + bias  (4x4 tile/thread) ----
        {
            const int ng = tid >> 4, mg = tid & 15;
            const int nb = ng*4, mb = mg*4;
            const float* Qp = &sQKV[(h*16)*64];
            const float* Kp = &sQKV[(48 + h*16)*64];
            float acc[4][4] = {};
            #pragma unroll
            for (int d = 0; d < 16; ++d) {
                float4 q4 = *(const float4*)&Qp[d*64 + nb];
                float4 k4 = *(const float4*)&Kp[d*64 + mb];
                float qr[4] = {q4.x, q4.y, q4.z, q4.w};
                float kr[4] = {k4.x, k4.y, k4.z, k4.w};
                #pragma unroll
                for (int r = 0; r < 4; ++r)
                    #pragma unroll
                    for (int cc = 0; cc < 4; ++cc)
                        acc[r][cc] += qr[r] * kr[cc];
            }
            const float* bh = biasws + h*4096;
            #pragma unroll
            for (int r = 0; r < 4; ++r) {
                float4 b4 = *(const float4*)&bh[(nb + r)*64 + mb];
                *(float4*)&S[(nb + r)*68 + mb] = make_float4(
                    acc[r][0]*scale + b4.x, acc[r][1]*scale + b4.y,
                    acc[r][2]*scale + b4.z, acc[r][3]*scale + b4.w);
            }
        }
        __syncthreads();

        // ---- softmax rows: 4 lanes per row, exp kept unnormalized + row sum ----
        {
            int n = tid >> 2, qq = tid & 3;
            float* row = &S[n*68 + qq*16];
            float4 a = *(float4*)&row[0];
            float4 b2 = *(float4*)&row[4];
            float4 c2 = *(float4*)&row[8];
            float4 d2 = *(float4*)&row[12];
            float mx = fmaxf(fmaxf(fmaxf(a.x,a.y), fmaxf(a.z,a.w)),
                      fmaxf(fmaxf(fmaxf(b2.x,b2.y), fmaxf(b2.z,b2.w)),
                      fmaxf(fmaxf(fmaxf(c2.x,c2.y), fmaxf(c2.z,c2.w)),
                            fmaxf(fmaxf(d2.x,d2.y), fmaxf(d2.z,d2.w)))));
            mx = fmaxf(mx, __shfl_xor(mx, 1));
            mx = fmaxf(mx, __shfl_xor(mx, 2));
            a.x = __expf(a.x-mx); a.y = __expf(a.y-mx); a.z = __expf(a.z-mx); a.w = __expf(a.w-mx);
            b2.x = __expf(b2.x-mx); b2.y = __expf(b2.y-mx); b2.z = __expf(b2.z-mx); b2.w = __expf(b2.w-mx);
            c2.x = __expf(c2.x-mx); c2.y = __expf(c2.y-mx); c2.z = __expf(c2.z-mx); c2.w = __expf(c2.w-mx);
            d2.x = __expf(d2.x-mx); d2.y = __expf(d2.y-mx); d2.z = __expf(d2.z-mx); d2.w = __expf(d2.w-mx);
            float s = a.x+a.y+a.z+a.w + b2.x+b2.y+b2.z+b2.w
                    + c2.x+c2.y+c2.z+c2.w + d2.x+d2.y+d2.z+d2.w;
            *(float4*)&row[0]  = a;  *(float4*)&row[4]  = b2;
            *(float4*)&row[8]  = c2; *(float4*)&row[12] = d2;
            s += __shfl_xor(s, 1);
            s += __shfl_xor(s, 2);
            if (qq == 0) sLsum[n] = s;
        }
        __syncthreads();

        // ---- PV: out[n][d] = (P[n][:] . v[d][:]) / lsum[n] ----
        {
            int n = tid >> 2, dg = tid & 3;
            float acc4[4] = {0.f, 0.f, 0.f, 0.f};
            const float* Vb = &sQKV[(96 + h*16 + dg*4)*64];
            const float* Sr = &S[n*68];
            #pragma unroll
            for (int m4 = 0; m4 < 16; ++m4) {
                float4 p4 = *(const float4*)&Sr[m4*4];
                #pragma unroll
                for (int j = 0; j < 4; ++j) {
                    float4 v4 = *(const float4*)&Vb[j*64 + m4*4];
                    acc4[j] += p4.x*v4.x + p4.y*v4.y + p4.z*v4.z + p4.w*v4.w;
                }
            }
            float rinv = 1.0f / sLsum[n];
            #pragma unroll
            for (int j = 0; j < 4; ++j)
                sXs[(h*16 + dg*4 + j)*64 + n] = acc4[j] * rinv;   // Os[c][p]
        }
        __syncthreads();
    }

    // ---- phase 4: out-proj + store (3x4 tile/thread) ----
    {
        const int og = tid >> 4, pg = tid & 15;
        const int ob = og*3, pb4 = pg*4;
        float acc[3][4];
        #pragma unroll
        for (int j = 0; j < 3; ++j) {
            float bv = sPb[ob + j];
            acc[j][0] = acc[j][1] = acc[j][2] = acc[j][3] = bv;
        }
        for (int c = 0; c < 48; ++c) {
            float4 x4 = *(const float4*)&sXs[c*64 + pb4];
            #pragma unroll
            for (int j = 0; j < 3; ++j) {
                float w = Pw[(ob + j)*48 + c];
                acc[j][0] += w * x4.x; acc[j][1] += w * x4.y;
                acc[j][2] += w * x4.z; acc[j][3] += w * x4.w;
            }
        }
        const int row = pb4 >> 3, col = pb4 & 7;
        float* op = out + ((size_t)batch * 48 << 18);
        #pragma unroll
        for (int j = 0; j < 3; ++j)
            *(float4*)&op[((size_t)(ob + j) << 18) + (size_t)(h0 + row)*512 + (w0 + col)] =
                make_float4(acc[j][0], acc[j][1], acc[j][2], acc[j][3]);
    }
}

extern "C" void kernel_launch(void* const* d_in, const int* in_sizes, int n_in,
                              void* d_out, int out_size, void* d_ws, size_t ws_size,
                              hipStream_t stream) {
    (void)n_in; (void)out_size; (void)ws_size;
    const float* X      = (const float*)d_in[0];
    const float* v_w    = (const float*)d_in[1];
    const float* v_b    = (const float*)d_in[2];
    const float* qk_w   = (const float*)d_in[3];
    const float* qk_b   = (const float*)d_in[4];
    const float* proj_w = (const float*)d_in[5];
    const float* proj_b = (const float*)d_in[6];
    const float* m1w    = (const float*)d_in[7];
    const float* m1b    = (const float*)d_in[8];
    const float* m2w    = (const float*)d_in[9];
    const float* m2b    = (const float*)d_in[10];
    float* out    = (float*)d_out;
    float* biasws = (float*)d_ws;   // 3*64*64 fp32 = 48 KB

    const int B = in_sizes[0] / (48 * 512 * 512);   // = 2

    hipLaunchKernelGGL(bias_mlp_kernel, dim3(16), dim3(256), 0, stream,
                       m1w, m1b, m2w, m2b, biasws);
    hipLaunchKernelGGL(win_attn_kernel, dim3(B * 64 * 64), dim3(256), 0, stream,
                       X, v_w, v_b, qk_w, qk_b, proj_w, proj_b, biasws, out);
}

// Round 2
// 538.341 us; speedup vs baseline: 1.2639x; 1.2639x over previous
//
#include <hip/hip_runtime.h>
#include <math.h>

// Swin-style window attention, WS=8, HEADS=3, C=48, hd=16, fp32.
// One 256-thread block per 8x8 window. LDS ~50 KB -> 3 blocks/CU.
// All LDS traffic: lane-stride-1 b32, padded b128 (bank-quads spread), or
// wave-uniform broadcasts. Scores live in registers (64/lane), softmax in-lane.

// ---------------- kernel 1: relative-position-bias MLP ----------------------
__global__ __launch_bounds__(256) void bias_mlp_kernel(
    const float* __restrict__ m1w, const float* __restrict__ m1b,
    const float* __restrict__ m2w, const float* __restrict__ m2b,
    float* __restrict__ biasws)
{
    int t = blockIdx.x * 256 + threadIdx.x;   // 0..4095 -> (n,m)
    int n = t >> 6, m = t & 63;
    float di = (float)((n >> 3) - (m >> 3));
    float dj = (float)((n & 7) - (m & 7));
    float r0 = copysignf(log1pf(fabsf(di)), di);
    float r1 = copysignf(log1pf(fabsf(dj)), dj);
    float a0 = 0.f, a1 = 0.f, a2 = 0.f;
    for (int k = 0; k < 256; ++k) {
        float hv = fmaxf(m1b[k] + m1w[2*k]*r0 + m1w[2*k+1]*r1, 0.f);
        a0 += m2w[k]     * hv;
        a1 += m2w[256+k] * hv;
        a2 += m2w[512+k] * hv;
    }
    biasws[t]        = a0 + m2b[0];
    biasws[4096 + t] = a1 + m2b[1];
    biasws[8192 + t] = a2 + m2b[2];
}

// ---------------- kernel 2: fused QKV + window attention + out-proj ---------
#define ST_STRIDE 148   // 144 + 4 pad: bank-quad = (37p+q)%8 = (5p+q)%8, spread

__global__ __launch_bounds__(256, 3) void win_attn_kernel(
    const float* __restrict__ X,
    const float* __restrict__ v_w,  const float* __restrict__ v_b,
    const float* __restrict__ qk_w, const float* __restrict__ qk_b,
    const float* __restrict__ proj_w, const float* __restrict__ proj_b,
    const float* __restrict__ biasws,
    float* __restrict__ out, int nblk)
{
    __shared__ float sX[48*64];           // [chan][token]; reused as attn-out
    __shared__ float sT[64*ST_STRIDE];    // [token][qkv-chan 0..143] transposed

    const int tid  = threadIdx.x;
    const int wave = tid >> 6;
    const int lane = tid & 63;

    // XCD swizzle: adjacent windows (sharing 64B X lines) -> same XCD slab
    const int blk = blockIdx.x;
    const int wid = (blk & 7) * (nblk >> 3) + (blk >> 3);
    const int batch = wid >> 12;
    const int wh = (wid >> 6) & 63, ww = wid & 63;
    const int h0 = wh << 3, w0 = ww << 3;

    const float* Xb = X + ((size_t)batch * 48 << 18);

    // ---- phase 1: stage X window [c][p], float4 global + stride-1 LDS ------
    #pragma unroll
    for (int k = 0; k < 3; ++k) {
        int i4 = tid + k*256;                 // 0..767 float4s
        int c = i4 >> 4, p4 = (i4 & 15) << 2; // token base
        float4 v = *(const float4*)&Xb[((size_t)c << 18)
                     + (size_t)(h0 + (p4 >> 3))*512 + (w0 + (p4 & 7))];
        *(float4*)&sX[c*64 + p4] = v;
    }
    __syncthreads();

    // ---- phase 2: QKV. wave=36 rows (scalar weights), lane=token ----------
    {
        float x[48];
        #pragma unroll
        for (int c = 0; c < 48; ++c) x[c] = sX[c*64 + lane];   // stride-1, free

        const int rb = __builtin_amdgcn_readfirstlane(wave) * 36;
        float acc[36];
        #pragma unroll
        for (int j = 0; j < 36; ++j) {
            const int row = rb + j;
            const float* wr = (row < 96) ? (qk_w + row*48) : (v_w + (row-96)*48);
            float a = (row < 96) ? qk_b[row] : v_b[row-96];
            #pragma unroll
            for (int c = 0; c < 48; ++c) a = fmaf(wr[c], x[c], a);
            acc[j] = a;
        }
        // write transposed: sT[token][chan], b128, bank-quads spread by pad
        #pragma unroll
        for (int b = 0; b < 9; ++b)
            *(float4*)&sT[lane*ST_STRIDE + rb + 4*b] =
                make_float4(acc[4*b], acc[4*b+1], acc[4*b+2], acc[4*b+3]);
    }
    __syncthreads();

    // ---- phase 3: attention. wave=head, lane=row n; scores in registers ---
    if (wave < 3) {
        const int h = __builtin_amdgcn_readfirstlane(wave);
        const int n = lane;
        const float* myrow = &sT[n*ST_STRIDE + h*16];

        float q[16];
        #pragma unroll
        for (int t = 0; t < 4; ++t) {
            float4 q4 = *(const float4*)&myrow[4*t];
            q[4*t]   = q4.x * 0.25f; q[4*t+1] = q4.y * 0.25f;
            q[4*t+2] = q4.z * 0.25f; q[4*t+3] = q4.w * 0.25f;
        }

        float s[64];
        #pragma unroll
        for (int m = 0; m < 64; ++m) {   // K rows: wave-uniform b128 broadcast
            const float* kr = &sT[m*ST_STRIDE + 48 + h*16];
            float4 k0 = *(const float4*)&kr[0];
            float4 k1 = *(const float4*)&kr[4];
            float4 k2 = *(const float4*)&kr[8];
            float4 k3 = *(const float4*)&kr[12];
            float a = q[0]*k0.x;
            a = fmaf(q[1],  k0.y, a); a = fmaf(q[2],  k0.z, a); a = fmaf(q[3],  k0.w, a);
            a = fmaf(q[4],  k1.x, a); a = fmaf(q[5],  k1.y, a); a = fmaf(q[6],  k1.z, a); a = fmaf(q[7],  k1.w, a);
            a = fmaf(q[8],  k2.x, a); a = fmaf(q[9],  k2.y, a); a = fmaf(q[10], k2.z, a); a = fmaf(q[11], k2.w, a);
            a = fmaf(q[12], k3.x, a); a = fmaf(q[13], k3.y, a); a = fmaf(q[14], k3.z, a); a = fmaf(q[15], k3.w, a);
            s[m] = a;
        }

        const float* bh = biasws + h*4096 + n*64;   // L2-hot, 48 KB total
        #pragma unroll
        for (int t = 0; t < 16; ++t) {
            float4 b4 = *(const float4*)&bh[4*t];
            s[4*t]   += b4.x; s[4*t+1] += b4.y;
            s[4*t+2] += b4.z; s[4*t+3] += b4.w;
        }

        // in-lane softmax (max tree, unnormalized exp, deferred divide)
        float tmx[32];
        #pragma unroll
        for (int i = 0; i < 32; ++i) tmx[i] = fmaxf(s[i], s[i+32]);
        #pragma unroll
        for (int st = 16; st >= 1; st >>= 1) {
            #pragma unroll
            for (int i = 0; i < st; ++i) tmx[i] = fmaxf(tmx[i], tmx[i+st]);
        }
        const float mx = tmx[0];
        float p0 = 0.f, p1 = 0.f, p2 = 0.f, p3 = 0.f;
        #pragma unroll
        for (int t = 0; t < 16; ++t) {
            s[4*t]   = __expf(s[4*t]  -mx); p0 += s[4*t];
            s[4*t+1] = __expf(s[4*t+1]-mx); p1 += s[4*t+1];
            s[4*t+2] = __expf(s[4*t+2]-mx); p2 += s[4*t+2];
            s[4*t+3] = __expf(s[4*t+3]-mx); p3 += s[4*t+3];
        }
        const float rinv = 1.0f / ((p0+p1)+(p2+p3));

        float o[16] = {0.f,0.f,0.f,0.f,0.f,0.f,0.f,0.f,
                       0.f,0.f,0.f,0.f,0.f,0.f,0.f,0.f};
        #pragma unroll
        for (int m = 0; m < 64; ++m) {   // V rows: wave-uniform b128 broadcast
            const float* vr = &sT[m*ST_STRIDE + 96 + h*16];
            float4 v0 = *(const float4*)&vr[0];
            float4 v1 = *(const float4*)&vr[4];
            float4 v2 = *(const float4*)&vr[8];
            float4 v3 = *(const float4*)&vr[12];
            const float pm = s[m];
            o[0]  = fmaf(pm, v0.x, o[0]);  o[1]  = fmaf(pm, v0.y, o[1]);
            o[2]  = fmaf(pm, v0.z, o[2]);  o[3]  = fmaf(pm, v0.w, o[3]);
            o[4]  = fmaf(pm, v1.x, o[4]);  o[5]  = fmaf(pm, v1.y, o[5]);
            o[6]  = fmaf(pm, v1.z, o[6]);  o[7]  = fmaf(pm, v1.w, o[7]);
            o[8]  = fmaf(pm, v2.x, o[8]);  o[9]  = fmaf(pm, v2.y, o[9]);
            o[10] = fmaf(pm, v2.z, o[10]); o[11] = fmaf(pm, v2.w, o[11]);
            o[12] = fmaf(pm, v3.x, o[12]); o[13] = fmaf(pm, v3.y, o[13]);
            o[14] = fmaf(pm, v3.z, o[14]); o[15] = fmaf(pm, v3.w, o[15]);
        }
        #pragma unroll
        for (int d = 0; d < 16; ++d)       // stride-1 across lanes, free
            sX[(h*16 + d)*64 + n] = o[d] * rinv;
    }
    __syncthreads();

    // ---- phase 4: out-proj. wave=12 rows (scalar weights), lane=token -----
    {
        float x[48];
        #pragma unroll
        for (int c = 0; c < 48; ++c) x[c] = sX[c*64 + lane];   // stride-1, free

        const int rb = __builtin_amdgcn_readfirstlane(wave) * 12;
        const int pr = lane >> 3, pc = lane & 7;
        #pragma unroll
        for (int j = 0; j < 12; ++j) {
            const int row = rb + j;
            const float* wr = proj_w + row*48;
            float a = proj_b[row];
            #pragma unroll
            for (int c = 0; c < 48; ++c) a = fmaf(wr[c], x[c], a);
            out[((size_t)(batch*48 + row) << 18)
                + (size_t)(h0 + pr)*512 + (w0 + pc)] = a;
        }
    }
}

extern "C" void kernel_launch(void* const* d_in, const int* in_sizes, int n_in,
                              void* d_out, int out_size, void* d_ws, size_t ws_size,
                              hipStream_t stream) {
    (void)n_in; (void)out_size; (void)ws_size;
    const float* X      = (const float*)d_in[0];
    const float* v_w    = (const float*)d_in[1];
    const float* v_b    = (const float*)d_in[2];
    const float* qk_w   = (const float*)d_in[3];
    const float* qk_b   = (const float*)d_in[4];
    const float* proj_w = (const float*)d_in[5];
    const float* proj_b = (const float*)d_in[6];
    const float* m1w    = (const float*)d_in[7];
    const float* m1b    = (const float*)d_in[8];
    const float* m2w    = (const float*)d_in[9];
    const float* m2b    = (const float*)d_in[10];
    float* out    = (float*)d_out;
    float* biasws = (float*)d_ws;   // 3*64*64 fp32 = 48 KB

    const int B = in_sizes[0] / (48 * 512 * 512);   // = 2
    const int nblk = B * 64 * 64;

    hipLaunchKernelGGL(bias_mlp_kernel, dim3(16), dim3(256), 0, stream,
                       m1w, m1b, m2w, m2b, biasws);
    hipLaunchKernelGGL(win_attn_kernel, dim3(nblk), dim3(256), 0, stream,
                       X, v_w, v_b, qk_w, qk_b, proj_w, proj_b, biasws, out, nblk);
}

// Round 4
// 280.358 us; speedup vs baseline: 2.4270x; 1.9202x over previous
//
#include <hip/hip_runtime.h>
#include <math.h>

// Swin window attention, WS=8, HEADS=3, C=48, hd=16. fp16 MFMA everywhere.
// One 256-thread block per 8x8 window; Sᵀ-form QK so P feeds PV from registers.

typedef _Float16 f16x4 __attribute__((ext_vector_type(4)));
typedef float    f32x4 __attribute__((ext_vector_type(4)));

// d_ws layout (bytes)
#define WS_BFRAG 0        // bias frags: 3 heads x 16 tiles x 64 lanes x f32x4 = 49152
#define WS_WFRAG 49152    // qkv W frags: 27 x 64 x f16x4 = 13824
#define WS_PFRAG 62976    // proj W frags: 9 x 64 x f16x4 = 4608
#define WS_QKVB  67584    // 144 f32
#define WS_PBIAS 68160    // 48 f32

// LDS strides (in halves; even-dword strides, 8B-aligned fragment reads)
#define XT_S 52   // X/O token rows [64][52]
#define T_S  100  // QK token rows  [64][100] (chans 0..95)
#define VD_S 68   // V d-major      [48][68]

// ---------------- prep: bias MLP + weight/bias fragment packing -------------
__global__ __launch_bounds__(256) void prep_kernel(
    const float* __restrict__ m1w, const float* __restrict__ m1b,
    const float* __restrict__ m2w, const float* __restrict__ m2b,
    const float* __restrict__ qk_w, const float* __restrict__ v_w,
    const float* __restrict__ proj_w,
    const float* __restrict__ qk_b, const float* __restrict__ v_b,
    const float* __restrict__ proj_b,
    unsigned char* __restrict__ ws)
{
    float*     bfrag = (float*)(ws + WS_BFRAG);
    _Float16*  wfrag = (_Float16*)(ws + WS_WFRAG);
    _Float16*  pfrag = (_Float16*)(ws + WS_PFRAG);
    float*     qkvb  = (float*)(ws + WS_QKVB);
    float*     pbias = (float*)(ws + WS_PBIAS);

    const int gid = blockIdx.x * 256 + threadIdx.x;
    if (gid < 4096) {
        // bias MLP for (n, m); scatter into Sᵀ C-layout fragment order
        const int n = gid >> 6, m = gid & 63;
        float di = (float)((n >> 3) - (m >> 3));
        float dj = (float)((n & 7) - (m & 7));
        float r0 = copysignf(log1pf(fabsf(di)), di);
        float r1 = copysignf(log1pf(fabsf(dj)), dj);
        float a0 = 0.f, a1 = 0.f, a2 = 0.f;
        for (int k = 0; k < 256; ++k) {
            float hv = fmaxf(m1b[k] + m1w[2*k]*r0 + m1w[2*k+1]*r1, 0.f);
            a0 += m2w[k]     * hv;
            a1 += m2w[256+k] * hv;
            a2 += m2w[512+k] * hv;
        }
        const int tm = m >> 4, quad = (m >> 2) & 3, r = m & 3, tn = n >> 4;
        const int ln = quad*16 + (n & 15);
        const int base = ((tm*4 + tn)*64 + ln)*4 + r;
        bfrag[(0*16*64)*4  + base] = a0 + m2b[0];
        bfrag[(16*64)*4    + base] = a1 + m2b[1];
        bfrag[(32*64)*4    + base] = a2 + m2b[2];
    } else if (gid < 4096 + 6912) {
        const int idx = gid - 4096;           // ((mt*3+ks)*64 + l)*4 + j
        const int j = idx & 3, l = (idx >> 2) & 63, f = idx >> 8;
        const int ks = f % 3, mt = f / 3;
        const int row = mt*16 + (l & 15), col = ks*16 + ((l >> 4) << 2) + j;
        const float wv = (row < 96) ? qk_w[row*48 + col] : v_w[(row-96)*48 + col];
        wfrag[idx] = (_Float16)wv;
    } else if (gid < 11008 + 2304) {
        const int idx = gid - 11008;
        const int j = idx & 3, l = (idx >> 2) & 63, f = idx >> 8;
        const int ks = f % 3, mt = f / 3;
        const int row = mt*16 + (l & 15), col = ks*16 + ((l >> 4) << 2) + j;
        pfrag[idx] = (_Float16)proj_w[row*48 + col];
    } else if (gid < 13312 + 144) {
        const int c = gid - 13312;
        qkvb[c] = (c < 96) ? qk_b[c] : v_b[c - 96];
    } else if (gid < 13456 + 48) {
        pbias[gid - 13456] = proj_b[gid - 13456];
    }
}

// ---------------- fused QKV + attention + proj, fp16 MFMA -------------------
__global__ __launch_bounds__(256, 4) void win_attn_kernel(
    const float* __restrict__ X, const unsigned char* __restrict__ ws,
    float* __restrict__ out, int nblk)
{
    __shared__ _Float16 smem[12992];          // 25984 B
    _Float16* sXO = smem;                     // [64][XT_S]: X f16; later Oᵀ
    _Float16* sT  = smem + 64*XT_S;           // [64][T_S]: Q chans 0..47, K 48..95
    _Float16* sVd = smem + 64*XT_S + 64*T_S;  // [48][VD_S]: V d-major

    const float* bfrag = (const float*)(ws + WS_BFRAG);
    const f16x4* wfrag = (const f16x4*)(ws + WS_WFRAG);
    const f16x4* pfrag = (const f16x4*)(ws + WS_PFRAG);
    const float* qkvb  = (const float*)(ws + WS_QKVB);
    const float* pbias = (const float*)(ws + WS_PBIAS);

    const int tid  = threadIdx.x;
    const int wave = tid >> 6, lane = tid & 63;
    const int lq   = lane >> 4, lm = lane & 15;

    const int blk = blockIdx.x;
    const int wid = (blk & 7) * (nblk >> 3) + (blk >> 3);   // XCD swizzle
    const int batch = wid >> 12;
    const int wh = (wid >> 6) & 63, ww = wid & 63;
    const int h0 = wh << 3, w0 = ww << 3;

    const float* Xb = X + ((size_t)batch * 48 << 18);

    // ---- phase 1: stage X window -> f16 token-major LDS --------------------
    {
        const int tok = lane;
        const size_t pix = (size_t)(h0 + (tok >> 3)) * 512 + (w0 + (tok & 7));
        #pragma unroll
        for (int k = 0; k < 12; ++k) {
            const int c = wave + (k << 2);
            sXO[tok*XT_S + c] = (_Float16)Xb[((size_t)c << 18) + pix];
        }
    }
    __syncthreads();

    // ---- phase 2: QKV GEMM [144x48]x[48x64]; wave w = tokens 16w..16w+15 ---
    {
        f16x4 bx[3];
        #pragma unroll
        for (int ks = 0; ks < 3; ++ks)
            bx[ks] = *(const f16x4*)&sXO[(wave*16 + lm)*XT_S + ks*16 + lq*4];
        f16x4 aw[27];
        #pragma unroll
        for (int f = 0; f < 27; ++f) aw[f] = wfrag[f*64 + lane];

        const int tok = wave*16 + lm;
        #pragma unroll
        for (int mt = 0; mt < 9; ++mt) {
            f32x4 acc = *(const f32x4*)&qkvb[mt*16 + lq*4];
            #pragma unroll
            for (int ks = 0; ks < 3; ++ks)
                acc = __builtin_amdgcn_mfma_f32_16x16x16f16(aw[mt*3+ks], bx[ks], acc, 0, 0, 0);
            if (mt < 3) {                      // Q: fold in 1/sqrt(hd)=0.25
                f16x4 hv;
                #pragma unroll
                for (int r = 0; r < 4; ++r) hv[r] = (_Float16)(acc[r] * 0.25f);
                *(f16x4*)&sT[tok*T_S + mt*16 + lq*4] = hv;
            } else if (mt < 6) {               // K
                f16x4 hv;
                #pragma unroll
                for (int r = 0; r < 4; ++r) hv[r] = (_Float16)acc[r];
                *(f16x4*)&sT[tok*T_S + mt*16 + lq*4] = hv;
            } else {                           // V -> d-major scatter
                #pragma unroll
                for (int r = 0; r < 4; ++r)
                    sVd[((mt-6)*16 + lq*4 + r)*VD_S + tok] = (_Float16)acc[r];
            }
        }
    }
    __syncthreads();

    // ---- phase 3: attention (wave = head). Sᵀ = K·Qᵀ; P stays in regs ------
    if (wave < 3) {
        const int h = wave;
        f16x4 ak[4], bq[4];
        #pragma unroll
        for (int t = 0; t < 4; ++t) {
            ak[t] = *(const f16x4*)&sT[(t*16 + lm)*T_S + 48 + h*16 + lq*4]; // K rows
            bq[t] = *(const f16x4*)&sT[(t*16 + lm)*T_S + h*16 + lq*4];     // Qᵀ cols
        }
        f32x4 s[4][4];                          // Sᵀ tiles [tm][tn], C = bias
        const f32x4* bf = (const f32x4*)bfrag + (size_t)h*16*64;
        #pragma unroll
        for (int tm = 0; tm < 4; ++tm)
            #pragma unroll
            for (int tn = 0; tn < 4; ++tn) {
                f32x4 c = bf[(tm*4 + tn)*64 + lane];
                s[tm][tn] = __builtin_amdgcn_mfma_f32_16x16x16f16(ak[tm], bq[tn], c, 0, 0, 0);
            }
        // softmax over m (rows of Sᵀ): 16 in-lane values + 2 shfls per tn
        float rinv[4];
        #pragma unroll
        for (int tn = 0; tn < 4; ++tn) {
            float mx = s[0][tn][0];
            #pragma unroll
            for (int tm = 0; tm < 4; ++tm)
                #pragma unroll
                for (int r = 0; r < 4; ++r) mx = fmaxf(mx, s[tm][tn][r]);
            mx = fmaxf(mx, __shfl_xor(mx, 16));
            mx = fmaxf(mx, __shfl_xor(mx, 32));
            float sum = 0.f;
            #pragma unroll
            for (int tm = 0; tm < 4; ++tm)
                #pragma unroll
                for (int r = 0; r < 4; ++r) {
                    float e = __expf(s[tm][tn][r] - mx);
                    s[tm][tn][r] = e; sum += e;
                }
            sum += __shfl_xor(sum, 16);
            sum += __shfl_xor(sum, 32);
            rinv[tn] = 1.f / sum;
        }
        // PV: Oᵀ = Vᵀ · Pᵀ ; Pᵀ C-regs are directly valid B-fragments
        f16x4 av[4];
        #pragma unroll
        for (int tm = 0; tm < 4; ++tm)
            av[tm] = *(const f16x4*)&sVd[(h*16 + lm)*VD_S + tm*16 + lq*4];
        #pragma unroll
        for (int tn = 0; tn < 4; ++tn) {
            f32x4 o = {0.f, 0.f, 0.f, 0.f};
            #pragma unroll
            for (int tm = 0; tm < 4; ++tm) {
                f16x4 pf;
                pf[0] = (_Float16)s[tm][tn][0];
                pf[1] = (_Float16)s[tm][tn][1];
                pf[2] = (_Float16)s[tm][tn][2];
                pf[3] = (_Float16)s[tm][tn][3];
                o = __builtin_amdgcn_mfma_f32_16x16x16f16(av[tm], pf, o, 0, 0, 0);
            }
            f16x4 hv;
            #pragma unroll
            for (int r = 0; r < 4; ++r) hv[r] = (_Float16)(o[r] * rinv[tn]);
            *(f16x4*)&sXO[(tn*16 + lm)*XT_S + h*16 + lq*4] = hv;   // Oᵀ rows=tok
        }
    }
    __syncthreads();

    // ---- phase 4: proj [48x48]x[48x64]; wave w = tokens 16w..16w+15 --------
    {
        f16x4 bo[3];
        #pragma unroll
        for (int ks = 0; ks < 3; ++ks)
            bo[ks] = *(const f16x4*)&sXO[(wave*16 + lm)*XT_S + ks*16 + lq*4];
        f16x4 ap[9];
        #pragma unroll
        for (int f = 0; f < 9; ++f) ap[f] = pfrag[f*64 + lane];

        const int tok = wave*16 + lm;
        float* ob = out + ((size_t)batch * 48 << 18);
        const size_t pix = (size_t)(h0 + (tok >> 3)) * 512 + (w0 + (tok & 7));
        #pragma unroll
        for (int mt = 0; mt < 3; ++mt) {
            f32x4 acc = *(const f32x4*)&pbias[mt*16 + lq*4];
            #pragma unroll
            for (int ks = 0; ks < 3; ++ks)
                acc = __builtin_amdgcn_mfma_f32_16x16x16f16(ap[mt*3+ks], bo[ks], acc, 0, 0, 0);
            #pragma unroll
            for (int r = 0; r < 4; ++r)
                ob[((size_t)(mt*16 + lq*4 + r) << 18) + pix] = acc[r];
        }
    }
}

extern "C" void kernel_launch(void* const* d_in, const int* in_sizes, int n_in,
                              void* d_out, int out_size, void* d_ws, size_t ws_size,
                              hipStream_t stream) {
    (void)n_in; (void)out_size; (void)ws_size;
    const float* X      = (const float*)d_in[0];
    const float* v_w    = (const float*)d_in[1];
    const float* v_b    = (const float*)d_in[2];
    const float* qk_w   = (const float*)d_in[3];
    const float* qk_b   = (const float*)d_in[4];
    const float* proj_w = (const float*)d_in[5];
    const float* proj_b = (const float*)d_in[6];
    const float* m1w    = (const float*)d_in[7];
    const float* m1b    = (const float*)d_in[8];
    const float* m2w    = (const float*)d_in[9];
    const float* m2b    = (const float*)d_in[10];
    float* out = (float*)d_out;
    unsigned char* ws = (unsigned char*)d_ws;   // ~68.4 KB used

    const int B = in_sizes[0] / (48 * 512 * 512);   // = 2
    const int nblk = B * 64 * 64;

    hipLaunchKernelGGL(prep_kernel, dim3(53), dim3(256), 0, stream,
                       m1w, m1b, m2w, m2b, qk_w, v_w, proj_w, qk_b, v_b, proj_b, ws);
    hipLaunchKernelGGL(win_attn_kernel, dim3(nblk), dim3(256), 0, stream,
                       X, ws, out, nblk);
}